// Round 2
// baseline (9066.480 us; speedup 1.0000x reference)
//
#include <hip/hip_runtime.h>
#include <hip/hip_bf16.h>

// ---------------------------------------------------------------------------
// LSTM: T=256, B=128, F=1024, H=1024.  gates = [x_t | h] @ [W_ih; W_hh] + bias
// Persistent kernel: 256 WGs (4 row-groups x 64 hcol-groups), wave = gate.
// bf16 MFMA 16x16x32, fp32 accum, fp32 cell state in LDS.
// GLOBAL generation barrier (single counter, agent-scope atomics).
//
// R1 fix: round 0 blindly wrote 16.8+ MiB into d_ws; ws_size is evidently
// smaller -> pack_w overflowed and clobbered the harness's pristine input
// copies (call 1 passed, all later calls deterministically wrong). Now the
// layout adapts to ws_size and NEVER writes past it:
//   tier A (ws >= ~81 MiB): counters | pB | pH | pX     (round-0 fast path)
//   tier B (ws >= ~17 MiB): counters | pB | pH          (x read fp32)
//   tier C (ws >= ~16 MiB+1K): counters | pB            (h read from out fp32)
//   tier D (ws <  16 MiB): weights packed into out rows [224,256) -- those
//          rows are only written at steps 224+, and the GLOBAL barrier keeps
//          all WGs on the same step, so reads (t<224) never race writes.
//          Steps 224..255 load weight fragments strided-fp32 from d_in.
// ---------------------------------------------------------------------------

typedef __attribute__((ext_vector_type(8))) short short8;   // 8 bf16 = 4 VGPRs
typedef __attribute__((ext_vector_type(4))) float floatx4;  // MFMA accumulator

#define HID_OFF 33554432L   // T*B*H
#define CT_OFF  33685504L   // T*B*H + B*H
#define WTAIL_F 29360128L   // 224*131072 : float offset of hid rows [224,256)

__device__ __forceinline__ unsigned short f2bf(float f) {
    __hip_bfloat16 hb = __float2bfloat16(f);
    return *reinterpret_cast<unsigned short*>(&hb);
}

// ---- pack weights into B-fragment order: frag=(nblk*64+kblk), lane, 8 bf16 ----
// B[k][n]: n = nblk*16 + (lane&15), k = kblk*32 + (lane>>4)*8 + j
__global__ void pack_w_kernel(const float* __restrict__ wih,
                              const float* __restrict__ whh,
                              unsigned short* __restrict__ pB) {
    int g    = blockIdx.x * 256 + threadIdx.x;   // 1,048,576 threads
    int lane = g & 63;
    int frag = g >> 6;
    int kblk = frag & 63;
    int nblk = frag >> 6;
    int n = nblk * 16 + (lane & 15);
    int k = kblk * 32 + ((lane >> 4) << 3);
    const float* src = (k < 1024) ? (wih + (size_t)k * 4096 + n)
                                  : (whh + (size_t)(k - 1024) * 4096 + n);
    __attribute__((aligned(16))) unsigned short tmp[8];
#pragma unroll
    for (int jj = 0; jj < 8; ++jj) tmp[jj] = f2bf(src[(size_t)jj * 4096]);
    *reinterpret_cast<uint4*>(pB + (size_t)frag * 512 + lane * 8) =
        *reinterpret_cast<const uint4*>(tmp);
}

// ---- pack x into A-fragment order: frag=(t*256 + mblk*32 + kblk) ----
__global__ void pack_x_kernel(const float* __restrict__ x,
                              unsigned short* __restrict__ pX) {
    int g    = blockIdx.x * 256 + threadIdx.x;   // 4,194,304 threads
    int lane = g & 63;
    int frag = g >> 6;
    int kblk = frag & 31;
    int mblk = (frag >> 5) & 7;
    int t    = frag >> 8;
    int m = mblk * 16 + (lane & 15);
    int k = kblk * 32 + ((lane >> 4) << 3);
    const float* src = x + (size_t)(t * 128 + m) * 1024 + k;
    float4 f0 = *reinterpret_cast<const float4*>(src);
    float4 f1 = *reinterpret_cast<const float4*>(src + 4);
    __attribute__((aligned(16))) unsigned short tmp[8];
    tmp[0] = f2bf(f0.x); tmp[1] = f2bf(f0.y); tmp[2] = f2bf(f0.z); tmp[3] = f2bf(f0.w);
    tmp[4] = f2bf(f1.x); tmp[5] = f2bf(f1.y); tmp[6] = f2bf(f1.z); tmp[7] = f2bf(f1.w);
    *reinterpret_cast<uint4*>(pX + (size_t)frag * 512 + lane * 8) =
        *reinterpret_cast<const uint4*>(tmp);
}

// ---- init packed h0 (broadcast over batch rows) ----
__global__ void pack_h0_kernel(const float* __restrict__ h0,
                               unsigned short* __restrict__ pH) {
    int g    = blockIdx.x * 256 + threadIdx.x;   // 16,384 threads
    int lane = g & 63;
    int frag = g >> 6;            // mblk*32 + kblk
    int kblk = frag & 31;
    int k = kblk * 32 + ((lane >> 4) << 3);
    __attribute__((aligned(16))) unsigned short tmp[8];
#pragma unroll
    for (int jj = 0; jj < 8; ++jj) tmp[jj] = f2bf(h0[k + jj]);
    *reinterpret_cast<uint4*>(pH + (size_t)frag * 512 + lane * 8) =
        *reinterpret_cast<const uint4*>(tmp);
}

// strided fp32 B-fragment gather (fallback for steps >= wcut in tier D)
__device__ __forceinline__ short8 bfrag_f32(const float* __restrict__ W,
                                            int n, int k0) {
    union { short8 v; unsigned short u[8]; } t;
    const float* p = W + (size_t)k0 * 4096 + n;
#pragma unroll
    for (int jj = 0; jj < 8; ++jj) t.u[jj] = f2bf(p[(size_t)jj * 4096]);
    return t.v;
}

// fp32 -> bf16x8 A-fragment from 8 contiguous floats
__device__ __forceinline__ short8 afrag_f32(const float* p) {
    float4 f0 = *reinterpret_cast<const float4*>(p);
    float4 f1 = *reinterpret_cast<const float4*>(p + 4);
    union { short8 v; unsigned short u[8]; } t;
    t.u[0] = f2bf(f0.x); t.u[1] = f2bf(f0.y); t.u[2] = f2bf(f0.z); t.u[3] = f2bf(f0.w);
    t.u[4] = f2bf(f1.x); t.u[5] = f2bf(f1.y); t.u[6] = f2bf(f1.z); t.u[7] = f2bf(f1.w);
    return t.v;
}

// ---- main persistent LSTM kernel ----
__global__ __launch_bounds__(256) void lstm_main(
    const float* __restrict__ x, const float* __restrict__ h0,
    const float* __restrict__ c0, const float* __restrict__ wih,
    const float* __restrict__ whh, const float* __restrict__ bias,
    const unsigned short* __restrict__ pB, int wcut,
    unsigned short* pH, int use_ph,
    const unsigned short* __restrict__ pX, int use_px,
    float* out, int* counters) {

    __shared__ float g_lds[4][32][17];          // activated gates (pad 17)
    __shared__ float c_lds[32][16];             // persistent fp32 cell state
    __shared__ unsigned short hbf_lds[32][16];  // bf16 h staging (use_ph only)

    const int tid  = threadIdx.x;
    const int lane = tid & 63;
    const int w    = tid >> 6;       // wave index == gate index (i,f,g,o)
    const int wg   = blockIdx.x;
    const int j    = wg & 63;        // h-col block (16 cols)
    const int r    = wg >> 6;        // row group (32 batch rows)
    const int col  = lane & 15;
    const int quad = lane >> 4;
    const int q8   = quad * 8;
    const int nblk = w * 64 + j;
    const int nw   = nblk * 16 + col;   // weight column for strided fallback

    const float breg = bias[w * 1024 + j * 16 + col];

    // init cell state (broadcast c0 over batch rows)
    {
        float cv = c0[j * 16 + (tid & 15)];
        int row = tid >> 4;          // 0..15
        c_lds[row][tid & 15]      = cv;
        c_lds[row + 16][tid & 15] = cv;
    }
    __syncthreads();

    const unsigned short* pBw = pB + (size_t)nblk * 64 * 512 + lane * 8;

    for (int t = 0; t < 256; ++t) {
        const bool wp = (t < wcut);       // packed weights valid this step
        floatx4 acc0 = {0.f, 0.f, 0.f, 0.f};
        floatx4 acc1 = {0.f, 0.f, 0.f, 0.f};

        // ---- x part of K (k = 0..1023) ----
        if (use_px) {
            const unsigned short* pXr =
                pX + ((size_t)(t * 8 + 2 * r) * 32) * 512 + lane * 8;
#pragma unroll 4
            for (int kb = 0; kb < 32; ++kb) {
                short8 a0 = *reinterpret_cast<const short8*>(pXr + kb * 512);
                short8 a1 = *reinterpret_cast<const short8*>(pXr + 16384 + kb * 512);
                short8 b  = wp ? *reinterpret_cast<const short8*>(pBw + kb * 512)
                               : bfrag_f32(wih, nw, kb * 32 + q8);
                acc0 = __builtin_amdgcn_mfma_f32_16x16x32_bf16(a0, b, acc0, 0, 0, 0);
                acc1 = __builtin_amdgcn_mfma_f32_16x16x32_bf16(a1, b, acc1, 0, 0, 0);
            }
        } else {
            const float* xr0 = x + (size_t)(t * 128 + 32 * r + col) * 1024 + q8;
#pragma unroll 2
            for (int kb = 0; kb < 32; ++kb) {
                short8 a0 = afrag_f32(xr0 + kb * 32);
                short8 a1 = afrag_f32(xr0 + 16384 + kb * 32);
                short8 b  = wp ? *reinterpret_cast<const short8*>(pBw + kb * 512)
                               : bfrag_f32(wih, nw, kb * 32 + q8);
                acc0 = __builtin_amdgcn_mfma_f32_16x16x32_bf16(a0, b, acc0, 0, 0, 0);
                acc1 = __builtin_amdgcn_mfma_f32_16x16x32_bf16(a1, b, acc1, 0, 0, 0);
            }
        }

        // ---- h part of K (k = 1024..2047) ----
        if (use_ph) {
            const unsigned short* pHr =
                pH + (size_t)(t & 1) * 131072 + (size_t)(2 * r) * 32 * 512 + lane * 8;
#pragma unroll 4
            for (int kb = 0; kb < 32; ++kb) {
                short8 a0 = *reinterpret_cast<const short8*>(pHr + kb * 512);
                short8 a1 = *reinterpret_cast<const short8*>(pHr + 16384 + kb * 512);
                short8 b  = wp ? *reinterpret_cast<const short8*>(pBw + (32 + kb) * 512)
                               : bfrag_f32(whh, nw, kb * 32 + q8);
                acc0 = __builtin_amdgcn_mfma_f32_16x16x32_bf16(a0, b, acc0, 0, 0, 0);
                acc1 = __builtin_amdgcn_mfma_f32_16x16x32_bf16(a1, b, acc1, 0, 0, 0);
            }
        } else if (t == 0) {
#pragma unroll 2
            for (int kb = 0; kb < 32; ++kb) {
                const float* hp = h0 + kb * 32 + q8;
                union { short8 v; unsigned short u[8]; } th;
#pragma unroll
                for (int jj = 0; jj < 8; ++jj) th.u[jj] = f2bf(hp[jj]);
                short8 b = wp ? *reinterpret_cast<const short8*>(pBw + (32 + kb) * 512)
                              : bfrag_f32(whh, nw, kb * 32 + q8);
                acc0 = __builtin_amdgcn_mfma_f32_16x16x32_bf16(th.v, b, acc0, 0, 0, 0);
                acc1 = __builtin_amdgcn_mfma_f32_16x16x32_bf16(th.v, b, acc1, 0, 0, 0);
            }
        } else {
            const float* hr0 = out + (size_t)(t - 1) * 131072 +
                               (size_t)(32 * r + col) * 1024 + q8;
#pragma unroll 2
            for (int kb = 0; kb < 32; ++kb) {
                short8 a0 = afrag_f32(hr0 + kb * 32);
                short8 a1 = afrag_f32(hr0 + 16384 + kb * 32);
                short8 b  = wp ? *reinterpret_cast<const short8*>(pBw + (32 + kb) * 512)
                               : bfrag_f32(whh, nw, kb * 32 + q8);
                acc0 = __builtin_amdgcn_mfma_f32_16x16x32_bf16(a0, b, acc0, 0, 0, 0);
                acc1 = __builtin_amdgcn_mfma_f32_16x16x32_bf16(a1, b, acc1, 0, 0, 0);
            }
        }

        // ---- epilogue: bias + activation into LDS ----
        // D layout (verified m89): row = quad*4 + rr, col = lane&15
#pragma unroll
        for (int rr = 0; rr < 4; ++rr) {
            float p0 = acc0[rr] + breg;
            float p1 = acc1[rr] + breg;
            float v0, v1;
            if (w == 2) { v0 = tanhf(p0); v1 = tanhf(p1); }
            else        { v0 = 1.f / (1.f + __expf(-p0)); v1 = 1.f / (1.f + __expf(-p1)); }
            g_lds[w][quad * 4 + rr][col]      = v0;
            g_lds[w][16 + quad * 4 + rr][col] = v1;
        }
        __syncthreads();

        // ---- cell update (fp32, WG-local) ----
        {
            const long hidbase = (long)t * 131072;  // t*B*H
#pragma unroll
            for (int p = 0; p < 2; ++p) {
                int row = p * 16 + (tid >> 4);
                int cc  = tid & 15;
                float iv = g_lds[0][row][cc];
                float fv = g_lds[1][row][cc];
                float gv = g_lds[2][row][cc];
                float ov = g_lds[3][row][cc];
                float cold = c_lds[row][cc];
                float cnew = fv * cold + iv * gv;
                float hv   = ov * tanhf(cnew);
                c_lds[row][cc] = cnew;
                if (use_ph) hbf_lds[row][cc] = f2bf(hv);
                int m = 32 * r + row;
                out[hidbase + (long)m * 1024 + j * 16 + cc] = hv;
                if (t == 255) {
                    out[HID_OFF + (long)m * 1024 + j * 16 + cc] = hv;
                    out[CT_OFF  + (long)m * 1024 + j * 16 + cc] = cnew;
                }
            }
        }

        // ---- store h bf16 into packed A-fragment layout (next buffer) ----
        if (use_ph && t < 255) {
            __syncthreads();
            if (tid < 64) {
                int ml = tid >> 1;                   // local row 0..31
                int cg = tid & 1;                    // col group (8 cols)
                int m    = 32 * r + ml;
                int kcol = j * 16 + cg * 8;
                int frag  = (2 * r + (ml >> 4)) * 32 + (kcol >> 5);
                int lanep = (m & 15) + 16 * ((kcol & 31) >> 3);
                unsigned short* dst =
                    pH + (size_t)((t & 1) ^ 1) * 131072 + (size_t)frag * 512 + lanep * 8;
                *reinterpret_cast<uint4*>(dst) =
                    *reinterpret_cast<const uint4*>(&hbf_lds[ml][cg * 8]);
            }
        }

        // ---- GLOBAL generation barrier (agent scope, G16) ----
        if (t < 255) {
            __syncthreads();   // drain all waves' global stores (vmcnt 0 at barrier)
            if (tid == 0) {
                __hip_atomic_fetch_add(counters, 1, __ATOMIC_RELEASE,
                                       __HIP_MEMORY_SCOPE_AGENT);
                int target = 256 * (t + 1);
                while (__hip_atomic_load(counters, __ATOMIC_ACQUIRE,
                                         __HIP_MEMORY_SCOPE_AGENT) < target) {
                    __builtin_amdgcn_s_sleep(4);
                }
            }
            __syncthreads();
        }
    }
}

extern "C" void kernel_launch(void* const* d_in, const int* in_sizes, int n_in,
                              void* d_out, int out_size, void* d_ws, size_t ws_size,
                              hipStream_t stream) {
    (void)in_sizes; (void)n_in; (void)out_size;
    const float* x    = (const float*)d_in[0];
    const float* h0   = (const float*)d_in[1];
    const float* c0   = (const float*)d_in[2];
    const float* wih  = (const float*)d_in[3];
    const float* whh  = (const float*)d_in[4];
    const float* bias = (const float*)d_in[5];
    float* out = (float*)d_out;

    char* ws = (char*)d_ws;
    int* counters = (int*)ws;                 // needs only 256 B of ws
    const size_t SZB = 2048ull * 4096 * 2;    // 16 MiB packed weights
    const size_t SZH = 2ull * 256 * 512 * 2;  // 512 KiB packed-h ping-pong
    const size_t SZX = 65536ull * 512 * 2;    // 64 MiB packed x

    size_t off = 1024;
    unsigned short* pB;
    int wcut;
    if (ws_size >= off + SZB) {               // tier A/B/C: weights in ws
        pB = (unsigned short*)(ws + off); off += SZB; wcut = 256;
    } else {                                  // tier D: weights in out tail
        pB = (unsigned short*)(out + WTAIL_F); wcut = 224;
    }
    int use_ph = (ws_size >= off + SZH) ? 1 : 0;
    unsigned short* pH = use_ph ? (unsigned short*)(ws + off) : (unsigned short*)0;
    if (use_ph) off += SZH;
    int use_px = (ws_size >= off + SZX) ? 1 : 0;
    unsigned short* pX = use_px ? (unsigned short*)(ws + off) : (unsigned short*)0;

    hipMemsetAsync(ws, 0, 256, stream);                       // barrier counter
    pack_w_kernel<<<4096, 256, 0, stream>>>(wih, whh, pB);
    if (use_ph) pack_h0_kernel<<<64, 256, 0, stream>>>(h0, pH);
    if (use_px) pack_x_kernel<<<16384, 256, 0, stream>>>(x, pX);

    lstm_main<<<dim3(256), dim3(256), 0, stream>>>(
        x, h0, c0, wih, whh, bias, pB, wcut, pH, use_ph, pX, use_px, out, counters);
}

// Round 3
// 6925.047 us; speedup vs baseline: 1.3092x; 1.3092x over previous
//
#include <hip/hip_runtime.h>
#include <hip/hip_bf16.h>

// ---------------------------------------------------------------------------
// LSTM: T=256, B=128, F=1024, H=1024.  gates = [x_t | h] @ [W_ih; W_hh] + bias
// Persistent kernel, 256 WGs. Swizzled mapping: r=(wg>>3)&3 (32-row group),
// j=(wg&7)*8+(wg>>5) (16-col group) -> per-XCD weight footprint 2 MiB.
// Wave = gate. bf16 MFMA 16x16x32, fp32 accum, fp32 cell state in LDS.
//
// R3 changes vs R2 (which was sync-bound at 34.6 us/step, MfmaUtil 2.5%):
//  - 4 independent row-group barriers; 8 spread sub-counters each; per-group
//    aggregator WG (j==0) gather-polls 8 counters with 8 lanes -> 1 release
//    flag. Polls are RELAXED + one acquire fence (no per-poll cache inv).
//  - LDS A-fragment staging (32 KiB chunk buffer): kills 4x redundant A loads
//    and 4x redundant f2bf across the gate waves.
//  - x-half GEMM for step t+1 computed between arrival and wait (no h dep),
//    hiding under barrier latency. Aggregator polls after its x-prefetch.
// Workspace tiers (never write past ws_size; R1 lesson):
//    counters(16K) | pB(16M) | pH(512K) | pX(64M), each only if it fits;
//    tier D: pB in out rows [224,256), strided-fp32 weights for t>=224.
// ---------------------------------------------------------------------------

typedef __attribute__((ext_vector_type(8))) short short8;   // 8 bf16 = 4 VGPRs
typedef __attribute__((ext_vector_type(4))) float floatx4;  // MFMA accumulator

#define HID_OFF 33554432L   // T*B*H
#define CT_OFF  33685504L   // T*B*H + B*H
#define WTAIL_F 29360128L   // 224*131072 : float offset of hid rows [224,256)

__device__ __forceinline__ unsigned short f2bf(float f) {
    __hip_bfloat16 hb = __float2bfloat16(f);
    return *reinterpret_cast<unsigned short*>(&hb);
}

// 8 contiguous fp32 -> 8 bf16 packed in a uint4
__device__ __forceinline__ uint4 pack8(const float* p) {
    float4 f0 = *reinterpret_cast<const float4*>(p);
    float4 f1 = *reinterpret_cast<const float4*>(p + 4);
    union { uint4 v; unsigned short u[8]; } t;
    t.u[0] = f2bf(f0.x); t.u[1] = f2bf(f0.y); t.u[2] = f2bf(f0.z); t.u[3] = f2bf(f0.w);
    t.u[4] = f2bf(f1.x); t.u[5] = f2bf(f1.y); t.u[6] = f2bf(f1.z); t.u[7] = f2bf(f1.w);
    return t.v;
}

// ---- pack weights into B-fragment order: frag=(nblk*64+kblk), lane, 8 bf16 ----
__global__ void pack_w_kernel(const float* __restrict__ wih,
                              const float* __restrict__ whh,
                              unsigned short* __restrict__ pB) {
    int g    = blockIdx.x * 256 + threadIdx.x;   // 1,048,576 threads
    int lane = g & 63;
    int frag = g >> 6;
    int kblk = frag & 63;
    int nblk = frag >> 6;
    int n = nblk * 16 + (lane & 15);
    int k = kblk * 32 + ((lane >> 4) << 3);
    const float* src = (k < 1024) ? (wih + (size_t)k * 4096 + n)
                                  : (whh + (size_t)(k - 1024) * 4096 + n);
    __attribute__((aligned(16))) unsigned short tmp[8];
#pragma unroll
    for (int jj = 0; jj < 8; ++jj) tmp[jj] = f2bf(src[(size_t)jj * 4096]);
    *reinterpret_cast<uint4*>(pB + (size_t)frag * 512 + lane * 8) =
        *reinterpret_cast<const uint4*>(tmp);
}

// ---- pack x into A-fragment order: frag=(t*256 + mblk*32 + kblk) ----
__global__ void pack_x_kernel(const float* __restrict__ x,
                              unsigned short* __restrict__ pX) {
    int g    = blockIdx.x * 256 + threadIdx.x;   // 4,194,304 threads
    int lane = g & 63;
    int frag = g >> 6;
    int kblk = frag & 31;
    int mblk = (frag >> 5) & 7;
    int t    = frag >> 8;
    int m = mblk * 16 + (lane & 15);
    int k = kblk * 32 + ((lane >> 4) << 3);
    *reinterpret_cast<uint4*>(pX + (size_t)frag * 512 + lane * 8) =
        pack8(x + (size_t)(t * 128 + m) * 1024 + k);
}

// ---- init packed h0 (broadcast over batch rows) ----
__global__ void pack_h0_kernel(const float* __restrict__ h0,
                               unsigned short* __restrict__ pH) {
    int g    = blockIdx.x * 256 + threadIdx.x;   // 16,384 threads
    int lane = g & 63;
    int frag = g >> 6;            // mblk*32 + kblk
    int kblk = frag & 31;
    int k = kblk * 32 + ((lane >> 4) << 3);
    __attribute__((aligned(16))) unsigned short tmp[8];
#pragma unroll
    for (int jj = 0; jj < 8; ++jj) tmp[jj] = f2bf(h0[k + jj]);
    *reinterpret_cast<uint4*>(pH + (size_t)frag * 512 + lane * 8) =
        *reinterpret_cast<const uint4*>(tmp);
}

// strided fp32 B-fragment gather (tier-D fallback for steps >= wcut)
__device__ __forceinline__ short8 bfrag_f32(const float* __restrict__ W,
                                            int n, int k0) {
    union { short8 v; unsigned short u[8]; } t;
    const float* p = W + (size_t)k0 * 4096 + n;
#pragma unroll
    for (int jj = 0; jj < 8; ++jj) t.u[jj] = f2bf(p[(size_t)jj * 4096]);
    return t.v;
}

// ---- main persistent LSTM kernel ----
__global__ __launch_bounds__(256) void lstm_main(
    const float* __restrict__ x, const float* __restrict__ h0,
    const float* __restrict__ c0, const float* __restrict__ wih,
    const float* __restrict__ whh, const float* __restrict__ bias,
    const unsigned short* __restrict__ pB, int wcut,
    unsigned short* pH, int use_ph,
    const unsigned short* __restrict__ pX, int use_px,
    float* out, int* cnt) {

    __shared__ __align__(16) unsigned short Abuf[2][16][512];  // 32 KiB A-frag chunk
    __shared__ float g_lds[4][32][17];                          // activated gates
    __shared__ float c_lds[32][16];                             // fp32 cell state
    __shared__ __align__(16) unsigned short hbf_lds[32][16];    // bf16 h staging

    const int tid  = threadIdx.x;
    const int lane = tid & 63;
    const int w    = tid >> 6;                 // wave index == gate (i,f,g,o)
    const int wg   = blockIdx.x;
    const int r    = (wg >> 3) & 3;            // row group (32 batch rows)
    const int j    = (wg & 7) * 8 + (wg >> 5); // h-col block (16 cols), XCD-swizzled
    const int col  = lane & 15;
    const int quad = lane >> 4;
    const int q8   = quad * 8;
    const int nblk = w * 64 + j;
    const int nw   = nblk * 16 + col;          // weight column (tier-D fallback)

    int* subp = cnt + (r * 8 + (j >> 3)) * 64;  // arrival sub-counter (256B spread)
    int* relp = cnt + (32 + r) * 64;            // release flag for row group
    const bool is_agg = (j == 0);

    const float breg = bias[w * 1024 + j * 16 + col];

    { // init cell state (broadcast c0 over batch rows)
        float cv = c0[j * 16 + (tid & 15)];
        int row = tid >> 4;
        c_lds[row][tid & 15]      = cv;
        c_lds[row + 16][tid & 15] = cv;
    }

    const unsigned short* pBw = pB + (size_t)nblk * 64 * 512 + lane * 8;

    // ---- helpers -----------------------------------------------------------
    auto stage_x_chunk = [&](int tt, int c) {
#pragma unroll
        for (int i = 0; i < 8; ++i) {
            int s = tid + 256 * i;                 // slot in [0,2048)
            int ln = s & 63, kbl = (s >> 6) & 15, mb = s >> 10;
            int kbg = c * 16 + kbl;
            if (use_px) {
                const unsigned short* src =
                    pX + (((size_t)(tt * 8 + 2 * r + mb) * 32 + kbg) * 512) + ln * 8;
                *reinterpret_cast<uint4*>(&Abuf[mb][kbl][ln * 8]) =
                    *reinterpret_cast<const uint4*>(src);
            } else {
                int m = 32 * r + mb * 16 + (ln & 15);
                int k = kbg * 32 + ((ln >> 4) << 3);
                *reinterpret_cast<uint4*>(&Abuf[mb][kbl][ln * 8]) =
                    pack8(x + (size_t)(tt * 128 + m) * 1024 + k);
            }
        }
    };

    auto stage_h_chunk = [&](int tt, int c) {
#pragma unroll
        for (int i = 0; i < 8; ++i) {
            int s = tid + 256 * i;
            int ln = s & 63, kbl = (s >> 6) & 15, mb = s >> 10;
            int kbg = c * 16 + kbl;
            if (use_ph) {
                const unsigned short* src = pH + (size_t)(tt & 1) * 131072 +
                    (((size_t)(2 * r + mb) * 32 + kbg) * 512) + ln * 8;
                *reinterpret_cast<uint4*>(&Abuf[mb][kbl][ln * 8]) =
                    *reinterpret_cast<const uint4*>(src);
            } else if (tt == 0) {
                int k = kbg * 32 + ((ln >> 4) << 3);
                union { uint4 v; unsigned short u[8]; } tv;
#pragma unroll
                for (int jj = 0; jj < 8; ++jj) tv.u[jj] = f2bf(h0[k + jj]);
                *reinterpret_cast<uint4*>(&Abuf[mb][kbl][ln * 8]) = tv.v;
            } else {
                int m = 32 * r + mb * 16 + (ln & 15);
                int k = kbg * 32 + ((ln >> 4) << 3);
                *reinterpret_cast<uint4*>(&Abuf[mb][kbl][ln * 8]) =
                    pack8(out + (size_t)(tt - 1) * 131072 + (size_t)m * 1024 + k);
            }
        }
    };

    auto mfma_chunk = [&](int kbB, int kbW, bool wp, const float* Wf,
                          floatx4& a0acc, floatx4& a1acc) {
#pragma unroll 4
        for (int kb = 0; kb < 16; ++kb) {
            short8 a0 = *reinterpret_cast<const short8*>(&Abuf[0][kb][lane * 8]);
            short8 a1 = *reinterpret_cast<const short8*>(&Abuf[1][kb][lane * 8]);
            short8 b  = wp ? *reinterpret_cast<const short8*>(pBw + (size_t)(kbB + kb) * 512)
                           : bfrag_f32(Wf, nw, (kbW + kb) * 32 + q8);
            a0acc = __builtin_amdgcn_mfma_f32_16x16x32_bf16(a0, b, a0acc, 0, 0, 0);
            a1acc = __builtin_amdgcn_mfma_f32_16x16x32_bf16(a1, b, a1acc, 0, 0, 0);
        }
    };
    // ------------------------------------------------------------------------

    floatx4 xa0 = {0.f, 0.f, 0.f, 0.f}, xa1 = {0.f, 0.f, 0.f, 0.f};

    // prologue: x-part for t=0
    {
        bool wp0 = (0 < wcut);
        __syncthreads();                       // c_lds init visible; Abuf free
        stage_x_chunk(0, 0); __syncthreads();
        mfma_chunk(0, 0, wp0, wih, xa0, xa1); __syncthreads();
        stage_x_chunk(0, 1); __syncthreads();
        mfma_chunk(16, 16, wp0, wih, xa0, xa1);
    }

    for (int t = 0; t < 256; ++t) {
        const bool wp = (t < wcut);
        floatx4 acc0 = xa0, acc1 = xa1;

        // ---- wait for h(t-1) release ----
        if (t > 0 && tid == 0) {
            while (__hip_atomic_load(relp, __ATOMIC_RELAXED,
                                     __HIP_MEMORY_SCOPE_AGENT) < t)
                __builtin_amdgcn_s_sleep(1);
            __builtin_amdgcn_fence(__ATOMIC_ACQUIRE, "agent");
        }
        __syncthreads();   // also separates last Abuf reads from stage_h writes

        // ---- h part of K (k = 1024..2047), chunked through LDS ----
        stage_h_chunk(t, 0); __syncthreads();
        mfma_chunk(32, 0, wp, whh, acc0, acc1); __syncthreads();
        stage_h_chunk(t, 1); __syncthreads();
        mfma_chunk(48, 16, wp, whh, acc0, acc1);

        // ---- epilogue: bias + activation into LDS ----
        // D layout (m89): row = quad*4 + rr, col = lane&15
#pragma unroll
        for (int rr = 0; rr < 4; ++rr) {
            float p0 = acc0[rr] + breg;
            float p1 = acc1[rr] + breg;
            float v0, v1;
            if (w == 2) { v0 = tanhf(p0); v1 = tanhf(p1); }
            else        { v0 = 1.f / (1.f + __expf(-p0)); v1 = 1.f / (1.f + __expf(-p1)); }
            g_lds[w][quad * 4 + rr][col]      = v0;
            g_lds[w][16 + quad * 4 + rr][col] = v1;
        }
        __syncthreads();

        // ---- cell update (fp32, WG-local) ----
        {
            const long hidbase = (long)t * 131072;
#pragma unroll
            for (int p = 0; p < 2; ++p) {
                int row = p * 16 + (tid >> 4);
                int cc  = tid & 15;
                float iv = g_lds[0][row][cc];
                float fv = g_lds[1][row][cc];
                float gv = g_lds[2][row][cc];
                float ov = g_lds[3][row][cc];
                float cold = c_lds[row][cc];
                float cnew = fv * cold + iv * gv;
                float hv   = ov * tanhf(cnew);
                c_lds[row][cc]   = cnew;
                hbf_lds[row][cc] = f2bf(hv);
                int m = 32 * r + row;
                out[hidbase + (long)m * 1024 + j * 16 + cc] = hv;
                if (t == 255) {
                    out[HID_OFF + (long)m * 1024 + j * 16 + cc] = hv;
                    out[CT_OFF  + (long)m * 1024 + j * 16 + cc] = cnew;
                }
            }
        }
        __syncthreads();   // drains all waves' out stores; hbf_lds ready

        if (t < 255) {
            // ---- publish h(t): packed bf16 store (wave 0) ----
            if (use_ph && tid < 64) {
                int ml = tid >> 1, cg = tid & 1;
                int m = 32 * r + ml, kcol = j * 16 + cg * 8;
                int frag  = (2 * r + (ml >> 4)) * 32 + (kcol >> 5);
                int lanep = (m & 15) + 16 * ((kcol & 31) >> 3);
                unsigned short* dst = pH + (size_t)((t & 1) ^ 1) * 131072 +
                                      (size_t)frag * 512 + lanep * 8;
                *reinterpret_cast<uint4*>(dst) =
                    *reinterpret_cast<const uint4*>(&hbf_lds[ml][cg * 8]);
            }
            // ---- arrive (release orders this wave's pH stores; out stores
            //      were drained by the __syncthreads above) ----
            if (tid == 0)
                __hip_atomic_fetch_add(subp, 1, __ATOMIC_RELEASE,
                                       __HIP_MEMORY_SCOPE_AGENT);

            // ---- x prefetch for t+1 (no h dependency; hides barrier) ----
            bool wp2 = (t + 1 < wcut);
            xa0 = (floatx4){0.f, 0.f, 0.f, 0.f};
            xa1 = (floatx4){0.f, 0.f, 0.f, 0.f};
            __syncthreads();
            stage_x_chunk(t + 1, 0); __syncthreads();
            mfma_chunk(0, 0, wp2, wih, xa0, xa1); __syncthreads();
            stage_x_chunk(t + 1, 1); __syncthreads();
            mfma_chunk(16, 16, wp2, wih, xa0, xa1);

            // ---- aggregator: gather-poll 8 sub-counters, publish release ----
            if (is_agg && tid < 8) {
                int* sp = cnt + (r * 8 + tid) * 64;
                int target = 8 * (t + 1);
                while (true) {
                    int v = __hip_atomic_load(sp, __ATOMIC_RELAXED,
                                              __HIP_MEMORY_SCOPE_AGENT);
                    if (__ballot(v >= target) == 0xFFull) break;
                    __builtin_amdgcn_s_sleep(1);
                }
                __builtin_amdgcn_fence(__ATOMIC_ACQUIRE, "agent");
                if (tid == 0)
                    __hip_atomic_store(relp, t + 1, __ATOMIC_RELEASE,
                                       __HIP_MEMORY_SCOPE_AGENT);
            }
        }
    }
}

extern "C" void kernel_launch(void* const* d_in, const int* in_sizes, int n_in,
                              void* d_out, int out_size, void* d_ws, size_t ws_size,
                              hipStream_t stream) {
    (void)in_sizes; (void)n_in; (void)out_size;
    const float* x    = (const float*)d_in[0];
    const float* h0   = (const float*)d_in[1];
    const float* c0   = (const float*)d_in[2];
    const float* wih  = (const float*)d_in[3];
    const float* whh  = (const float*)d_in[4];
    const float* bias = (const float*)d_in[5];
    float* out = (float*)d_out;

    char* ws = (char*)d_ws;
    int* counters = (int*)ws;                 // 16 KiB counter region (spread lines)
    const size_t SZB = 2048ull * 4096 * 2;    // 16 MiB packed weights
    const size_t SZH = 2ull * 256 * 512 * 2;  // 512 KiB packed-h ping-pong
    const size_t SZX = 65536ull * 512 * 2;    // 64 MiB packed x

    size_t off = 16384;
    unsigned short* pB;
    int wcut;
    if (ws_size >= off + SZB) {               // weights in ws
        pB = (unsigned short*)(ws + off); off += SZB; wcut = 256;
    } else {                                  // tier D: weights in out tail
        pB = (unsigned short*)(out + WTAIL_F); wcut = 224;
    }
    int use_ph = (ws_size >= off + SZH) ? 1 : 0;
    unsigned short* pH = use_ph ? (unsigned short*)(ws + off) : (unsigned short*)0;
    if (use_ph) off += SZH;
    int use_px = (ws_size >= off + SZX) ? 1 : 0;
    unsigned short* pX = use_px ? (unsigned short*)(ws + off) : (unsigned short*)0;

    hipMemsetAsync(ws, 0, 16384, stream);                     // barrier counters
    pack_w_kernel<<<4096, 256, 0, stream>>>(wih, whh, pB);
    if (use_ph) pack_h0_kernel<<<64, 256, 0, stream>>>(h0, pH);
    if (use_px) pack_x_kernel<<<16384, 256, 0, stream>>>(x, pX);

    lstm_main<<<dim3(256), dim3(256), 0, stream>>>(
        x, h0, c0, wih, whh, bias, pB, wcut, pH, use_ph, pX, use_px, out, counters);
}